// Round 1
// baseline (5836.662 us; speedup 1.0000x reference)
//
#include <hip/hip_runtime.h>
#include <hip/hip_bf16.h>

#define BB 4096
#define TT 512
#define HH 256

typedef __bf16 bf16x8 __attribute__((ext_vector_type(8)));
typedef float f32x4 __attribute__((ext_vector_type(4)));

// Reorder w_hh [1024][256] fp32 -> bf16 fragment-ordered buffer:
// wB[kt][ct][lane][e] = w_hh[ct*16 + (lane&15)][kt*32 + 8*(lane>>4) + e]
// so each wave's B-fragment load is one coalesced 16B/lane read.
__global__ void prep_weights(const float* __restrict__ w_hh, __bf16* __restrict__ wB) {
    int idx = blockIdx.x * blockDim.x + threadIdx.x;
    if (idx >= 8 * 64 * 64) return;
    int lane = idx & 63;
    int ct = (idx >> 6) & 63;
    int kt = idx >> 12;
    int n = ct * 16 + (lane & 15);
    int k0 = kt * 32 + 8 * (lane >> 4);
    const float* src = w_hh + n * HH + k0;
    __bf16* dst = wB + (size_t)idx * 8;
#pragma unroll
    for (int e = 0; e < 8; ++e) dst[e] = (__bf16)src[e];
}

__device__ __forceinline__ float sigmoid_f(float v) { return 1.f / (1.f + __expf(-v)); }
// NaN-safe tanh: 1 - 2/(exp(2v)+1) (handles exp overflow -> 1.0)
__device__ __forceinline__ float tanh_f(float v) { float e = __expf(2.f * v); return 1.f - 2.f / (e + 1.f); }

__global__ __launch_bounds__(512, 2) void lstm_fused(
    const float* __restrict__ x, const float* __restrict__ eps,
    const float* __restrict__ w_ih, const float* __restrict__ b_ih,
    const float* __restrict__ b_hh, const float* __restrict__ w_mean,
    const float* __restrict__ b_mean, const float* __restrict__ w_logvar,
    const float* __restrict__ b_logvar, const __bf16* __restrict__ wB,
    float* __restrict__ out)
{
    __shared__ __bf16 gates[16][1032];                 // 33 KB, padded stride
    __shared__ __align__(16) __bf16 hbuf[16][264];     // 8.4 KB, padded stride (528B, 16B-aligned)
    __shared__ float wih_s[1024];
    __shared__ float bias_s[1024];
    __shared__ float wm_s[256];
    __shared__ float wlv_s[256];
    __shared__ float xb[16], eb[16], mb[16], lvb[16];

    const int tid = threadIdx.x;
    const int w = tid >> 6;          // wave id 0..7
    const int l = tid & 63;          // lane
    const int m0 = blockIdx.x * 16;  // batch base

    for (int i = tid; i < 1024; i += 512) { wih_s[i] = w_ih[i]; bias_s[i] = b_ih[i] + b_hh[i]; }
    for (int i = tid; i < 256; i += 512)  { wm_s[i] = w_mean[i]; wlv_s[i] = w_logvar[i]; }
    for (int i = tid; i < 16 * 264; i += 512) (&hbuf[0][0])[i] = (__bf16)0.f;

    const float bm = b_mean[0], blv = b_logvar[0];

    // elementwise ownership: batch row em, hidden units eu..eu+7; c persistent in regs
    const int em = tid >> 5;
    const int eu = (tid & 31) * 8;
    float c[8];
#pragma unroll
    for (int j = 0; j < 8; ++j) c[j] = 0.f;

    float* out_s = out;
    float* out_m = out + (size_t)BB * TT;
    float* out_lv = out + (size_t)2 * BB * TT;

    const int arow = l & 15;
    const int ako = 8 * (l >> 4);

    __syncthreads();

    for (int t = 0; t < TT; ++t) {
        if (tid < 16) {
            xb[tid] = x[(size_t)(m0 + tid) * TT + t];
            eb[tid] = eps[(size_t)(m0 + tid) * TT + t];
        }

        // ---- GEMM: gates[16][1024] = h(bf16) @ w_hh^T(bf16), fp32 accum ----
        bf16x8 af[8];
#pragma unroll
        for (int kt = 0; kt < 8; ++kt)
            af[kt] = *(const bf16x8*)&hbuf[arow][kt * 32 + ako];

#pragma unroll
        for (int cc = 0; cc < 8; ++cc) {
            const int ctg = w * 8 + cc;  // global col-tile 0..63
            f32x4 acc = {0.f, 0.f, 0.f, 0.f};
#pragma unroll
            for (int kt = 0; kt < 8; ++kt) {
                bf16x8 bfr = ((const bf16x8*)wB)[(kt * 64 + ctg) * 64 + l];
                acc = __builtin_amdgcn_mfma_f32_16x16x32_bf16(af[kt], bfr, acc, 0, 0, 0);
            }
            const int col = ctg * 16 + (l & 15);
            const int r0 = (l >> 4) * 4;
#pragma unroll
            for (int j = 0; j < 4; ++j)
                gates[r0 + j][col] = (__bf16)acc[j];
        }
        __syncthreads();

        // ---- elementwise: LSTM cell update ----
        {
            const float xm = xb[em];
            bf16x8 hv;
#pragma unroll
            for (int j = 0; j < 8; ++j) {
                const int u = eu + j;
                float gi = (float)gates[em][u]       + xm * wih_s[u]       + bias_s[u];
                float gf = (float)gates[em][u + 256] + xm * wih_s[u + 256] + bias_s[u + 256];
                float gg = (float)gates[em][u + 512] + xm * wih_s[u + 512] + bias_s[u + 512];
                float go = (float)gates[em][u + 768] + xm * wih_s[u + 768] + bias_s[u + 768];
                float ia = sigmoid_f(gi), fa = sigmoid_f(gf), ga = tanh_f(gg), oa = sigmoid_f(go);
                float cn = fa * c[j] + ia * ga;
                c[j] = cn;
                hv[j] = (__bf16)(oa * tanh_f(cn));
            }
            *(bf16x8*)&hbuf[em][eu] = hv;
        }
        __syncthreads();

        // ---- heads: wave0 -> mean, wave1 -> logvar (4 lanes per batch row) ----
        if (w < 2) {
            const float* wv = (w == 0) ? wm_s : wlv_s;
            const int m = l >> 2, q = l & 3;
            const __bf16* hr = &hbuf[m][q * 64];
            const float* wr = wv + q * 64;
            float s = 0.f;
#pragma unroll
            for (int k = 0; k < 64; ++k) s += (float)hr[k] * wr[k];
            s += __shfl_xor(s, 1);
            s += __shfl_xor(s, 2);
            if (q == 0) {
                if (w == 0) mb[m] = s + bm;
                else lvb[m] = fminf(fmaxf(s + blv, -10.f), 2.f);
            }
        }
        __syncthreads();

        // ---- sample + store ----
        if (tid < 16) {
            const float mean = mb[tid], lv = lvb[tid];
            const size_t o = (size_t)(m0 + tid) * TT + t;
            out_s[o] = mean + __expf(0.5f * lv) * eb[tid];
            out_m[o] = mean;
            out_lv[o] = lv;
        }
        // no extra barrier needed: mb/lvb/eb reads are separated from their next
        // writers by barrier1/barrier2 of the next iteration (see hazard analysis)
    }
}

extern "C" void kernel_launch(void* const* d_in, const int* in_sizes, int n_in,
                              void* d_out, int out_size, void* d_ws, size_t ws_size,
                              hipStream_t stream) {
    const float* x = (const float*)d_in[0];
    const float* eps = (const float*)d_in[1];
    const float* w_ih = (const float*)d_in[2];
    const float* w_hh = (const float*)d_in[3];
    const float* b_ih = (const float*)d_in[4];
    const float* b_hh = (const float*)d_in[5];
    const float* w_mean = (const float*)d_in[6];
    const float* b_mean = (const float*)d_in[7];
    const float* w_logvar = (const float*)d_in[8];
    const float* b_logvar = (const float*)d_in[9];

    __bf16* wB = (__bf16*)d_ws;  // 512 KB fragment-ordered bf16 weights

    prep_weights<<<128, 256, 0, stream>>>(w_hh, wB);
    lstm_fused<<<256, 512, 0, stream>>>(x, eps, w_ih, b_ih, b_hh, w_mean, b_mean,
                                        w_logvar, b_logvar, wB, (float*)d_out);
}

// Round 2
// 2754.566 us; speedup vs baseline: 2.1189x; 2.1189x over previous
//
#include <hip/hip_runtime.h>
#include <hip/hip_bf16.h>

#define BB 4096
#define TT 512
#define HH 256

typedef __bf16 bf16x8 __attribute__((ext_vector_type(8)));
typedef float f32x4 __attribute__((ext_vector_type(4)));

#define NREG 16   // fragments per wave held in VGPRs
#define NLDS 15   // fragments per wave held in LDS
// remaining 33 fragments per wave streamed from L2 each step

// Reorder w_hh [1024][256] fp32 -> bf16 fragment-ordered buffer:
// frag (ctg,kt), lane l, elem e = w_hh[ctg*16 + (l&15)][kt*32 + 8*(l>>4) + e]
// stored at wB[((ctg*8+kt)*64 + l)*8 + e] so each frag load is one dwordx4/lane.
__global__ void prep_weights(const float* __restrict__ w_hh, __bf16* __restrict__ wB) {
    int idx = blockIdx.x * blockDim.x + threadIdx.x;
    if (idx >= 64 * 8 * 64) return;
    int l = idx & 63;
    int kt = (idx >> 6) & 7;
    int ctg = idx >> 9;
    int n = ctg * 16 + (l & 15);
    int k0 = kt * 32 + 8 * (l >> 4);
    const float* src = w_hh + n * HH + k0;
    __bf16* dst = wB + (size_t)idx * 8;
#pragma unroll
    for (int e = 0; e < 8; ++e) dst[e] = (__bf16)src[e];
}

__device__ __forceinline__ float sigmoid_f(float v) { return 1.f / (1.f + __expf(-v)); }
// NaN-safe tanh: 1 - 2/(exp(2v)+1) (handles exp overflow -> 1.0)
__device__ __forceinline__ float tanh_f(float v) { float e = __expf(2.f * v); return 1.f - 2.f / (e + 1.f); }

__global__ __launch_bounds__(512, 2) void lstm_fused(
    const float* __restrict__ x, const float* __restrict__ eps,
    const float* __restrict__ w_ih, const float* __restrict__ b_ih,
    const float* __restrict__ b_hh, const float* __restrict__ w_mean,
    const float* __restrict__ b_mean, const float* __restrict__ w_logvar,
    const float* __restrict__ b_logvar, const __bf16* __restrict__ wB,
    float* __restrict__ out)
{
    __shared__ __align__(16) __bf16 wlds[8][NLDS][512];   // 122880 B: LDS-resident frags
    __shared__ __align__(16) __bf16 hbuf[16][264];        // 8448 B, padded stride
    __shared__ __align__(16) __bf16 headw[8][512];        // 8192 B: head col-tile frags
    __shared__ float wih_s[1024];
    __shared__ float bias_s[1024];
    __shared__ float obuf[3][16][16];                     // 3072 B: 16-step output batch
    __shared__ float xb[16];

    const int tid = threadIdx.x;
    const int w = tid >> 6;          // wave 0..7
    const int l = tid & 63;
    const int m0 = blockIdx.x * 16;  // batch base

    for (int i = tid; i < 1024; i += 512) { wih_s[i] = w_ih[i]; bias_s[i] = b_ih[i] + b_hh[i]; }
    for (int i = tid; i < 16 * 264; i += 512) (&hbuf[0][0])[i] = (__bf16)0.f;

    // head column-tile: B-frag col 0 = w_mean, col 1 = w_logvar, cols 2-15 zero
    {
        int kt = tid >> 6, hl = tid & 63;  // 512 threads = 8 kt x 64 lanes
        int col = hl & 15;
        int k0 = kt * 32 + 8 * (hl >> 4);
        bf16x8 hw;
#pragma unroll
        for (int e = 0; e < 8; ++e) {
            float v = 0.f;
            if (col == 0) v = w_mean[k0 + e];
            else if (col == 1) v = w_logvar[k0 + e];
            hw[e] = (__bf16)v;
        }
        *(bf16x8*)&headw[kt][hl * 8] = hw;
    }

    // wave w owns ctg = w + 8p + 16g for cc = p*4+g (all 4 gates of its units)
    bf16x8 wreg[NREG];
#pragma unroll
    for (int cc = 0; cc < 8; ++cc) {
        const int ctg = w + 8 * (cc >> 2) + 16 * (cc & 3);
#pragma unroll
        for (int kt = 0; kt < 8; ++kt) {
            const int fi = cc * 8 + kt;
            if (fi < NREG + NLDS) {
                bf16x8 v = *(const bf16x8*)(wB + ((size_t)(ctg * 8 + kt) * 64 + l) * 8);
                if (fi < NREG) wreg[fi] = v;
                else *(bf16x8*)&wlds[w][fi - NREG][l * 8] = v;
            }
        }
    }

    const float bm = b_mean[0], blv = b_logvar[0];
    const int arow = l & 15;
    const int ako = 8 * (l >> 4);
    const int r0 = (l >> 4) * 4;

    float c[2][4];
#pragma unroll
    for (int p = 0; p < 2; ++p)
#pragma unroll
        for (int j = 0; j < 4; ++j) c[p][j] = 0.f;

    __syncthreads();

    for (int t = 0; t <= TT; ++t) {
        // ---- read h_{t-1} A-frags (before anyone overwrites hbuf) ----
        bf16x8 af[8];
#pragma unroll
        for (int kt = 0; kt < 8; ++kt)
            af[kt] = *(const bf16x8*)&hbuf[arow][kt * 32 + ako];
        if (tid < 16 && t < TT) xb[tid] = x[(size_t)(m0 + tid) * TT + t];
        __syncthreads();

        // ---- gates GEMM: fp32 accs stay in registers ----
        f32x4 accs[8];
        if (t < TT) {
#pragma unroll
            for (int cc = 0; cc < 8; ++cc) {
                const int ctg = w + 8 * (cc >> 2) + 16 * (cc & 3);
                f32x4 acc = {0.f, 0.f, 0.f, 0.f};
#pragma unroll
                for (int kt = 0; kt < 8; ++kt) {
                    const int fi = cc * 8 + kt;
                    bf16x8 bfr;
                    if (fi < NREG) bfr = wreg[fi];
                    else if (fi < NREG + NLDS) bfr = *(const bf16x8*)&wlds[w][fi - NREG][l * 8];
                    else bfr = *(const bf16x8*)(wB + ((size_t)(ctg * 8 + kt) * 64 + l) * 8);
                    acc = __builtin_amdgcn_mfma_f32_16x16x32_bf16(af[kt], bfr, acc, 0, 0, 0);
                }
                accs[cc] = acc;
            }
        }

        // ---- heads for h_{t-1} (wave 0, one step deferred) ----
        if (w == 0 && t >= 1) {
            f32x4 acch = {0.f, 0.f, 0.f, 0.f};
#pragma unroll
            for (int kt = 0; kt < 8; ++kt)
                acch = __builtin_amdgcn_mfma_f32_16x16x32_bf16(
                    af[kt], *(const bf16x8*)&headw[kt][l * 8], acch, 0, 0, 0);
            const int slot = (t - 1) & 15;
#pragma unroll
            for (int j = 0; j < 4; ++j) {
                float lvn = __shfl(acch[j], (l & 48) | 1);  // logvar sits in col-1 lane
                if ((l & 15) == 0) {
                    const int r = r0 + j;
                    float mean = acch[j] + bm;
                    float lv = fminf(fmaxf(lvn + blv, -10.f), 2.f);
                    float ev = eps[(size_t)(m0 + r) * TT + (t - 1)];
                    obuf[0][r][slot] = mean + __expf(0.5f * lv) * ev;
                    obuf[1][r][slot] = mean;
                    obuf[2][r][slot] = lv;
                }
            }
        }

        // ---- elementwise LSTM cell, fully in registers ----
        if (t < TT) {
            float xv[4];
#pragma unroll
            for (int j = 0; j < 4; ++j) xv[j] = xb[r0 + j];
#pragma unroll
            for (int p = 0; p < 2; ++p) {
                const int u = 128 * p + 16 * w + (l & 15);
                const float wi0 = wih_s[u], wi1 = wih_s[256 + u],
                            wi2 = wih_s[512 + u], wi3 = wih_s[768 + u];
                const float bi0 = bias_s[u], bi1 = bias_s[256 + u],
                            bi2 = bias_s[512 + u], bi3 = bias_s[768 + u];
#pragma unroll
                for (int j = 0; j < 4; ++j) {
                    float gi = accs[p * 4 + 0][j] + xv[j] * wi0 + bi0;
                    float gf = accs[p * 4 + 1][j] + xv[j] * wi1 + bi1;
                    float gg = accs[p * 4 + 2][j] + xv[j] * wi2 + bi2;
                    float go = accs[p * 4 + 3][j] + xv[j] * wi3 + bi3;
                    float ia = sigmoid_f(gi), fa = sigmoid_f(gf);
                    float ga = tanh_f(gg), oa = sigmoid_f(go);
                    float cn = fa * c[p][j] + ia * ga;
                    c[p][j] = cn;
                    hbuf[r0 + j][u] = (__bf16)(oa * tanh_f(cn));
                }
            }
        }

        // ---- coalesced output flush every 16 steps ----
        if ((t & 15) == 0 && t > 0) {
            __syncthreads();  // wave0's obuf writes -> flushing waves
            if (tid < 192) {
                const int o = tid >> 6, rr = (tid >> 2) & 15, q = tid & 3;
                f32x4 v = *(const f32x4*)&obuf[o][rr][q * 4];
                float* dst = out + (size_t)o * BB * TT + (size_t)(m0 + rr) * TT + (t - 16) + q * 4;
                *(f32x4*)dst = v;
            }
        }
        __syncthreads();
    }
}

extern "C" void kernel_launch(void* const* d_in, const int* in_sizes, int n_in,
                              void* d_out, int out_size, void* d_ws, size_t ws_size,
                              hipStream_t stream) {
    const float* x = (const float*)d_in[0];
    const float* eps = (const float*)d_in[1];
    const float* w_ih = (const float*)d_in[2];
    const float* w_hh = (const float*)d_in[3];
    const float* b_ih = (const float*)d_in[4];
    const float* b_hh = (const float*)d_in[5];
    const float* w_mean = (const float*)d_in[6];
    const float* b_mean = (const float*)d_in[7];
    const float* w_logvar = (const float*)d_in[8];
    const float* b_logvar = (const float*)d_in[9];

    __bf16* wB = (__bf16*)d_ws;  // 512 KB fragment-ordered bf16 weights

    prep_weights<<<128, 256, 0, stream>>>(w_hh, wB);
    lstm_fused<<<256, 512, 0, stream>>>(x, eps, w_ih, b_ih, b_hh, w_mean, b_mean,
                                        w_logvar, b_logvar, wB, (float*)d_out);
}